// Round 7
// baseline (166.604 us; speedup 1.0000x reference)
//
#include <hip/hip_runtime.h>
#include <math.h>
#include <stdint.h>

// B,H,W,C = 4,384,384,48; KERNEL=3 -> 128x128 output, 48 "channels" g.
// Output F=((b*128+r)*128+cc)*48+g consumes 9 contiguous floats at input row
// (b*384+3r+kr), float offset cc*144+(g&15)*9, kr=g>>4.
// Block = (b, r, kr, c8): 16 cc x 16 g = 256 outputs. Each of the 4 waves is
// fully PRIVATE: stages its own 4cc x 144 floats (2304 B) via async
// global_load_lds (width 16), waits only its own vmcnt(0) -- NO __syncthreads
// anywhere (kills barrier-convoy + barrier-drain stalls).
#define EPS 1e-4f
#define AS_G __attribute__((address_space(1)))
#define AS_L __attribute__((address_space(3)))

static __device__ __forceinline__ float rcp_f(float a) {
    return __builtin_amdgcn_rcpf(a);                 // v_rcp_f32, 1 ulp
}
// 64 lanes x 16 B: gaddr per-lane, LDS dest = wave-uniform base + lane*16
static __device__ __forceinline__ void g2lds16(const float* g, float* l) {
    __builtin_amdgcn_global_load_lds(
        (const AS_G uint32_t*)(uintptr_t)g,
        (AS_L uint32_t*)(uint32_t)(uintptr_t)l,   // low 32 bits = LDS offset
        16, 0, 0);
}

__global__ __launch_bounds__(256)
void fuzzy_pool_kernel(const float* __restrict__ x, float* __restrict__ out) {
    __shared__ float s[2304];                  // 4 waves x 576 floats

    const int tid  = threadIdx.x;
    const int wv   = tid >> 6;                 // wave 0..3
    const int lane = tid & 63;

    const int bid = blockIdx.x;                // ((b*128+r)*3 + kr)*8 + c8
    const int c8 = bid & 7;
    const int t1 = bid >> 3;
    const int kr = t1 % 3;                     // scalar magic-mul
    const int t2 = t1 / 3;
    const int r  = t2 & 127;
    const int b  = t2 >> 7;

    const int cc0 = c8 * 16 + wv * 4;          // this wave's first cc
    const float* __restrict__ src =
        x + ((size_t)(b * 384 + 3 * r + kr) * 18432 + cc0 * 144);
    float* lw = s + wv * 576;                  // wave-private LDS region

    // ---- async global -> LDS, wave-private: 2304 B = 2 full + 1 masked ----
    g2lds16(src +        lane * 4, lw);
    g2lds16(src + 256 +  lane * 4, lw + 256);
    if (lane < 16) g2lds16(src + 512 + lane * 4, lw + 512);
    __builtin_amdgcn_s_waitcnt(0x0F70);        // vmcnt(0) only, THIS wave; no barrier

    // lane = (cl = cc offset 0..3)*16 + (j = g' 0..15)
    const int cl = lane >> 4;
    const int j  = lane & 15;
    const float* __restrict__ vp = lw + cl * 144 + j * 9;  // 2-way banks: free

    float v[9];
#pragma unroll
    for (int t = 0; t < 9; ++t) v[t] = vp[t];

    const float R3 = 1.0f/3.0f, R5 = 0.2f, R7 = 1.0f/7.0f, R9 = 1.0f/9.0f;
    const float NC = -0.5f * 1.44269504088896340736f;   // -0.5*log2(e)

    // ---- membership(x): nested sums ----
    const float s3 = v[3] + v[4] + v[5];
    const float s5 = s3 + v[2] + v[6];
    const float s7 = s5 + v[1] + v[7];
    const float s9 = s7 + v[0] + v[8];
    const float m3 = s3 * R3, m5 = s5 * R5, m7 = s7 * R7, m9 = s9 * R9;
    const float v4v = v[4];

    const float v_avg = (m7 + m5 + m3 + v4v + m9) * R5;

    // ---- omega = |x - v_avg|; var = membership(omega) + eps ----
    float w9[9];
#pragma unroll
    for (int t = 0; t < 9; ++t) w9[t] = fabsf(v[t] - v_avg);

    const float t3 = w9[3] + w9[4] + w9[5];
    const float t5 = t3 + w9[2] + w9[6];
    const float t7 = t5 + w9[1] + w9[7];
    const float t9 = t7 + w9[0] + w9[8];
    const float var4 = t9 * R9 + EPS;          // var[...,4] (m_only_var probe)

    const float c0 = NC * rcp_f(t7 * R7 + EPS);
    const float c1 = NC * rcp_f(t5 * R5 + EPS);
    const float c2 = NC * rcp_f(t3 * R3 + EPS);
    const float c3 = NC * rcp_f(w9[4] + EPS);
    const float c4 = NC * rcp_f(var4);

    // ---- t-outer, j-inner; fold sums/maxes immediately (no arrays).
    // Fold orders bit-identical to R5: sum = ((((p0+p1)+p2)+p3)+p4) with the
    // (j=3,t=4) slot = exact 1.0; max left-fold j=0..4; thresh left-fold over
    // t=0,1,2,3,5,6,7,8; ms left-fold t=0..8; sn/sd ascending t. ----
    float thresh = 0.f, ms = 0.f, sn = 0.f, sd = 0.f;
#pragma unroll
    for (int t = 0; t < 9; ++t) {
        const float vt = v[t];
        const float d0 = vt - m7;  const float p0 = __builtin_amdgcn_exp2f(c0 * d0 * d0);
        const float d1 = vt - m5;  const float p1 = __builtin_amdgcn_exp2f(c1 * d1 * d1);
        const float d2 = vt - m3;  const float p2 = __builtin_amdgcn_exp2f(c2 * d2 * d2);
        float p3;
        if (t == 4) {
            p3 = 1.0f;                         // d = v4-v4 = +-0 -> 2^-0 = 1 exactly
        } else {
            const float d3 = vt - v4v;  p3 = __builtin_amdgcn_exp2f(c3 * d3 * d3);
        }
        const float d4 = vt - m9;  const float p4 = __builtin_amdgcn_exp2f(c4 * d4 * d4);

        const float sum = (((p0 + p1) + p2) + p3) + p4;
        if (t != 4) {                          // max_pi[4] = 1.0 >= all: drop from min
            const float mx = fmaxf(fmaxf(fmaxf(fmaxf(p0, p1), p2), p3), p4);
            thresh = (t == 0) ? mx : fminf(thresh, mx);
        }
        ms = (t == 0) ? sum : fmaxf(ms, sum);
        sn += sum * vt;
        sd += sum;
    }

    // any_t(sum*0.2 > thresh) <=> max_t(sum)*0.2 > thresh (monotone rounding);
    // the 0.2 cancels in the denoise ratio (matches R5, passed at 0.0039)
    const float denoised = sn * rcp_f(sd);
    const float res = ((ms * R5) > thresh) ? m9
                      : ((var4 < EPS) ? v_avg : denoised);

    const size_t S0 = ((size_t)((b * 128 + r) * 128 + cc0)) * 48 + kr * 16;
    out[S0 + cl * 48 + j] = res;
}

extern "C" void kernel_launch(void* const* d_in, const int* in_sizes, int n_in,
                              void* d_out, int out_size, void* d_ws, size_t ws_size,
                              hipStream_t stream) {
    (void)in_sizes; (void)n_in; (void)d_ws; (void)ws_size; (void)out_size;
    const float* x = (const float*)d_in[0];
    float* out = (float*)d_out;
    const int blocks = 4 * 128 * 3 * 8;   // (b, r, kr, c8) = 12288
    fuzzy_pool_kernel<<<blocks, 256, 0, stream>>>(x, out);
}